// Round 1
// baseline (2723.020 us; speedup 1.0000x reference)
//
#include <hip/hip_runtime.h>
#include <math.h>

#define NN 10000
#define NE 320000

static_assert(sizeof(float4) == 16, "");

__device__ __forceinline__ float gelu_exact(float x) {
  return 0.5f * x * (1.0f + erff(x * 0.70710678118654752f));
}

// ======================= 1. geometry =======================
// block = 256 threads = 16 edges x 16 o-channels, 4 reps -> 64 edges/block
__global__ __launch_bounds__(256) void geom_kernel(
    const float* __restrict__ hVv, const int* __restrict__ eidx,
    const float* __restrict__ frames, const float* __restrict__ Wvec,
    float* __restrict__ vff, float* __restrict__ partial)
{
  __shared__ float vcat[16][33][3];   // padded: stride 99 floats per edge-slot
  __shared__ float red[16][17];
  const int tid = threadIdx.x;
  const int o = tid & 15, el = tid >> 4;
  float wrow[32];
#pragma unroll
  for (int v = 0; v < 32; ++v) wrow[v] = Wvec[o * 32 + v];
  float s1 = 0.f, s2 = 0.f;
  for (int rep = 0; rep < 4; ++rep) {
    const int e = blockIdx.x * 64 + rep * 16 + el;
    const int c = eidx[e];
    const int d = eidx[NE + e];
    const float* F = frames + (size_t)e * 9;
    const float f0=F[0],f1=F[1],f2=F[2],f3=F[3],f4=F[4],f5=F[5],f6=F[6],f7=F[7],f8=F[8];
    const float* vd = hVv + (size_t)d * 48 + o * 3;
    const float vd0 = vd[0], vd1 = vd[1], vd2 = vd[2];
    const float t0 = f0*vd0 + f1*vd1 + f2*vd2;
    const float t1 = f3*vd0 + f4*vd1 + f5*vd2;
    const float t2 = f6*vd0 + f7*vd1 + f8*vd2;
    const float* vs = hVv + (size_t)c * 48 + o * 3;
    vcat[el][o][0] = t0; vcat[el][o][1] = t1; vcat[el][o][2] = t2;
    vcat[el][16 + o][0] = vs[0]; vcat[el][16 + o][1] = vs[1]; vcat[el][16 + o][2] = vs[2];
    __syncthreads();
    float ve0 = t0, ve1 = t1, ve2 = t2;   // v_edge = W_vec @ v_cat + v_dst_t
#pragma unroll
    for (int v = 0; v < 32; ++v) {
      const float w = wrow[v];
      ve0 = fmaf(w, vcat[el][v][0], ve0);
      ve1 = fmaf(w, vcat[el][v][1], ve1);
      ve2 = fmaf(w, vcat[el][v][2], ve2);
    }
    const float dist = sqrtf(ve0*ve0 + ve1*ve1 + ve2*ve2) + 1e-6f;
    const float inv = 1.0f / dist;
    float* vrow = vff + (size_t)e * 64;
    vrow[o*3+0] = ve0 * inv; vrow[o*3+1] = ve1 * inv; vrow[o*3+2] = ve2 * inv;
    vrow[48 + o] = dist;   // raw dist; BN applied later
    s1 += dist; s2 += dist * dist;
    __syncthreads();
  }
  red[el][o] = s1;
  __syncthreads();
  if (el == 0) {
    float t = 0.f;
#pragma unroll
    for (int j = 0; j < 16; ++j) t += red[j][o];
    partial[blockIdx.x * 32 + o] = t;
  }
  __syncthreads();
  red[el][o] = s2;
  __syncthreads();
  if (el == 0) {
    float t = 0.f;
#pragma unroll
    for (int j = 0; j < 16; ++j) t += red[j][o];
    partial[blockIdx.x * 32 + 16 + o] = t;
  }
}

// ======================= 2. BN finalize =======================
__global__ __launch_bounds__(512) void bn_finalize(
    const float* __restrict__ partial, const float* __restrict__ bn_g,
    const float* __restrict__ bn_b, float* __restrict__ bnp)
{
  __shared__ float a1[32][16];
  __shared__ float a2[32][16];
  const int t = threadIdx.x;
  const int o = t & 15, c = t >> 4;
  float s1 = 0.f, s2 = 0.f;
  for (int b = c; b < 5000; b += 32) {
    s1 += partial[b * 32 + o];
    s2 += partial[b * 32 + 16 + o];
  }
  a1[c][o] = s1; a2[c][o] = s2;
  __syncthreads();
  if (t < 16) {
    double S1 = 0.0, S2 = 0.0;
    for (int j = 0; j < 32; ++j) { S1 += a1[j][t]; S2 += a2[j][t]; }
    const double mu = S1 / (double)NE;
    const double var = S2 / (double)NE - mu * mu;   // population var (ddof=0)
    const float invs = (float)(1.0 / sqrt(var + 1e-5));
    const float sc = bn_g[t] * invs;
    bnp[t] = sc;
    bnp[16 + t] = bn_b[t] - (float)mu * sc;
  }
}

// shared inner-product micro-kernel macro: 4 rows x (4+4) cols
#define INNER_FMA(A0,A1,A2,A3,P,Q)                                            \
  acc[0][0]=fmaf(A0,P.x,acc[0][0]); acc[0][1]=fmaf(A0,P.y,acc[0][1]);         \
  acc[0][2]=fmaf(A0,P.z,acc[0][2]); acc[0][3]=fmaf(A0,P.w,acc[0][3]);         \
  acc[0][4]=fmaf(A0,Q.x,acc[0][4]); acc[0][5]=fmaf(A0,Q.y,acc[0][5]);         \
  acc[0][6]=fmaf(A0,Q.z,acc[0][6]); acc[0][7]=fmaf(A0,Q.w,acc[0][7]);         \
  acc[1][0]=fmaf(A1,P.x,acc[1][0]); acc[1][1]=fmaf(A1,P.y,acc[1][1]);         \
  acc[1][2]=fmaf(A1,P.z,acc[1][2]); acc[1][3]=fmaf(A1,P.w,acc[1][3]);         \
  acc[1][4]=fmaf(A1,Q.x,acc[1][4]); acc[1][5]=fmaf(A1,Q.y,acc[1][5]);         \
  acc[1][6]=fmaf(A1,Q.z,acc[1][6]); acc[1][7]=fmaf(A1,Q.w,acc[1][7]);         \
  acc[2][0]=fmaf(A2,P.x,acc[2][0]); acc[2][1]=fmaf(A2,P.y,acc[2][1]);         \
  acc[2][2]=fmaf(A2,P.z,acc[2][2]); acc[2][3]=fmaf(A2,P.w,acc[2][3]);         \
  acc[2][4]=fmaf(A2,Q.x,acc[2][4]); acc[2][5]=fmaf(A2,Q.y,acc[2][5]);         \
  acc[2][6]=fmaf(A2,Q.z,acc[2][6]); acc[2][7]=fmaf(A2,Q.w,acc[2][7]);         \
  acc[3][0]=fmaf(A3,P.x,acc[3][0]); acc[3][1]=fmaf(A3,P.y,acc[3][1]);         \
  acc[3][2]=fmaf(A3,P.z,acc[3][2]); acc[3][3]=fmaf(A3,P.w,acc[3][3]);         \
  acc[3][4]=fmaf(A3,Q.x,acc[3][4]); acc[3][5]=fmaf(A3,Q.y,acc[3][5]);         \
  acc[3][6]=fmaf(A3,Q.z,acc[3][6]); acc[3][7]=fmaf(A3,Q.w,acc[3][7]);

// ======================= 3. hE = [vff_bn | h_E] @ W_red =======================
// grid (5000, 2): 64-edge row tile, 128-col block. thread = 4 rows x 8 cols.
__global__ __launch_bounds__(256) void gemm_hE(
    const float* __restrict__ vff, const float* __restrict__ hEin,
    const float* __restrict__ Wred, const float* __restrict__ bnp,
    float* __restrict__ hEout)
{
  __shared__ float As[64][17];
  __shared__ float Bs[16][128];
  const int tid = threadIdx.x;
  const int tn = tid & 15, tm = tid >> 4;
  const size_t e0 = (size_t)blockIdx.x * 64;
  const int nb = blockIdx.y * 128;
  const int ar = tid >> 2, aq = (tid & 3) * 4;
  const int bk = tid >> 4, bc = (tid & 15) * 8;
  float acc[4][8];
#pragma unroll
  for (int r = 0; r < 4; ++r)
#pragma unroll
    for (int cc = 0; cc < 8; ++cc) acc[r][cc] = 0.f;

  for (int kc = 0; kc < 20; ++kc) {
    const int k0 = kc * 16;
    float4 av;
    if (k0 < 64) {
      av = *(const float4*)&vff[(e0 + ar) * 64 + k0 + aq];
      if (k0 + aq >= 48) {           // dist channels: apply BN scale/shift
        const int bi = k0 + aq - 48;
        av.x = fmaf(av.x, bnp[bi+0], bnp[16+bi+0]);
        av.y = fmaf(av.y, bnp[bi+1], bnp[16+bi+1]);
        av.z = fmaf(av.z, bnp[bi+2], bnp[16+bi+2]);
        av.w = fmaf(av.w, bnp[bi+3], bnp[16+bi+3]);
      }
    } else {
      av = *(const float4*)&hEin[(e0 + ar) * 256 + (k0 - 64) + aq];
    }
    const float4 b0 = *(const float4*)&Wred[(size_t)(k0 + bk) * 256 + nb + bc];
    const float4 b1 = *(const float4*)&Wred[(size_t)(k0 + bk) * 256 + nb + bc + 4];
    __syncthreads();
    As[ar][aq+0] = av.x; As[ar][aq+1] = av.y; As[ar][aq+2] = av.z; As[ar][aq+3] = av.w;
    *(float4*)&Bs[bk][bc] = b0;
    *(float4*)&Bs[bk][bc + 4] = b1;
    __syncthreads();
#pragma unroll
    for (int k = 0; k < 16; ++k) {
      const float a0 = As[tm*4+0][k], a1 = As[tm*4+1][k];
      const float a2 = As[tm*4+2][k], a3 = As[tm*4+3][k];
      const float4 p = *(const float4*)&Bs[k][tn*4];
      const float4 q = *(const float4*)&Bs[k][64 + tn*4];
      INNER_FMA(a0,a1,a2,a3,p,q)
    }
  }
#pragma unroll
  for (int r = 0; r < 4; ++r) {
    const size_t row = e0 + tm*4 + r;
    float4 u = make_float4(acc[r][0], acc[r][1], acc[r][2], acc[r][3]);
    float4 v = make_float4(acc[r][4], acc[r][5], acc[r][6], acc[r][7]);
    *(float4*)&hEout[row * 256 + nb + tn*4] = u;
    *(float4*)&hEout[row * 256 + nb + 64 + tn*4] = v;
  }
}

// ======================= 4. attention MLP (Wb1->Wb2->Wb3[:,:4]) =======================
__global__ __launch_bounds__(256) void attn_mlp(
    const float* __restrict__ hE, const float* __restrict__ hV,
    const int* __restrict__ eidx,
    const float* __restrict__ Wb1, const float* __restrict__ bb1,
    const float* __restrict__ Wb2, const float* __restrict__ bb2,
    const float* __restrict__ Wb3, const float* __restrict__ bb3,
    float* __restrict__ logits)
{
  __shared__ float X[64][129];
  __shared__ float As[64][17];
  __shared__ float Bs[16][128];
  const int tid = threadIdx.x;
  const int tn = tid & 15, tm = tid >> 4;
  const size_t e0 = (size_t)blockIdx.x * 64;
  const int ar = tid >> 2, aq = (tid & 3) * 4;
  const int bk = tid >> 4, bc = (tid & 15) * 8;
  float acc[4][8];
#pragma unroll
  for (int r = 0; r < 4; ++r)
#pragma unroll
    for (int cc = 0; cc < 8; ++cc) acc[r][cc] = 0.f;

  // --- GEMM: x1 = relu([h_V[center] | hE] @ Wb1 + bb1), K = 384 ---
  for (int kc = 0; kc < 24; ++kc) {
    const int k0 = kc * 16;
    float4 av;
    if (k0 < 128) {
      const int c = eidx[e0 + ar];
      av = *(const float4*)&hV[(size_t)c * 128 + k0 + aq];
    } else {
      av = *(const float4*)&hE[(e0 + ar) * 256 + (k0 - 128) + aq];
    }
    const float4 b0 = *(const float4*)&Wb1[(size_t)(k0 + bk) * 128 + bc];
    const float4 b1 = *(const float4*)&Wb1[(size_t)(k0 + bk) * 128 + bc + 4];
    __syncthreads();
    As[ar][aq+0] = av.x; As[ar][aq+1] = av.y; As[ar][aq+2] = av.z; As[ar][aq+3] = av.w;
    *(float4*)&Bs[bk][bc] = b0;
    *(float4*)&Bs[bk][bc + 4] = b1;
    __syncthreads();
#pragma unroll
    for (int k = 0; k < 16; ++k) {
      const float a0 = As[tm*4+0][k], a1 = As[tm*4+1][k];
      const float a2 = As[tm*4+2][k], a3 = As[tm*4+3][k];
      const float4 p = *(const float4*)&Bs[k][tn*4];
      const float4 q = *(const float4*)&Bs[k][64 + tn*4];
      INNER_FMA(a0,a1,a2,a3,p,q)
    }
  }
  {
    const int cA = tn*4, cB = 64 + tn*4;
#pragma unroll
    for (int r = 0; r < 4; ++r) {
      const int row = tm*4 + r;
#pragma unroll
      for (int i = 0; i < 4; ++i) {
        X[row][cA+i] = fmaxf(acc[r][i]   + bb1[cA+i], 0.f);
        X[row][cB+i] = fmaxf(acc[r][4+i] + bb1[cB+i], 0.f);
        acc[r][i] = 0.f; acc[r][4+i] = 0.f;
      }
    }
  }
  // --- GEMM: x2 = relu(x1 @ Wb2 + bb2), K = 128, A in LDS ---
  for (int kc = 0; kc < 8; ++kc) {
    const int k0 = kc * 16;
    const float4 b0 = *(const float4*)&Wb2[(size_t)(k0 + bk) * 128 + bc];
    const float4 b1 = *(const float4*)&Wb2[(size_t)(k0 + bk) * 128 + bc + 4];
    __syncthreads();
    *(float4*)&Bs[bk][bc] = b0;
    *(float4*)&Bs[bk][bc + 4] = b1;
    __syncthreads();
#pragma unroll
    for (int k = 0; k < 16; ++k) {
      const int kk = k0 + k;
      const float a0 = X[tm*4+0][kk], a1 = X[tm*4+1][kk];
      const float a2 = X[tm*4+2][kk], a3 = X[tm*4+3][kk];
      const float4 p = *(const float4*)&Bs[k][tn*4];
      const float4 q = *(const float4*)&Bs[k][64 + tn*4];
      INNER_FMA(a0,a1,a2,a3,p,q)
    }
  }
  __syncthreads();   // all x1 reads done before overwrite
  {
    const int cA = tn*4, cB = 64 + tn*4;
#pragma unroll
    for (int r = 0; r < 4; ++r) {
      const int row = tm*4 + r;
#pragma unroll
      for (int i = 0; i < 4; ++i) {
        X[row][cA+i] = fmaxf(acc[r][i]   + bb2[cA+i], 0.f);
        X[row][cB+i] = fmaxf(acc[r][4+i] + bb2[cB+i], 0.f);
      }
    }
  }
  __syncthreads();
  // --- logits = (x2 @ Wb3[:, :4] + bb3[:4]) / sqrt(32) ---
  const int le = tid >> 2, lh = tid & 3;
  float dot = bb3[lh];
  for (int k = 0; k < 128; ++k) dot = fmaf(X[le][k], Wb3[k * 8 + lh], dot);
  logits[(e0 + le) * 4 + lh] = dot * 0.17677669529663687f;
}

// ======================= 5. value MLP (Wv1->Wv2->Wv3) =======================
__global__ __launch_bounds__(256) void v_mlp(
    const float* __restrict__ hE,
    const float* __restrict__ Wv1, const float* __restrict__ bv1,
    const float* __restrict__ Wv2, const float* __restrict__ bv2,
    const float* __restrict__ Wv3, const float* __restrict__ bv3,
    float* __restrict__ Vout)
{
  __shared__ float X[64][129];
  __shared__ float As[64][17];
  __shared__ float Bs[16][128];
  const int tid = threadIdx.x;
  const int tn = tid & 15, tm = tid >> 4;
  const size_t e0 = (size_t)blockIdx.x * 64;
  const int ar = tid >> 2, aq = (tid & 3) * 4;
  const int bk = tid >> 4, bc = (tid & 15) * 8;
  float acc[4][8];
#pragma unroll
  for (int r = 0; r < 4; ++r)
#pragma unroll
    for (int cc = 0; cc < 8; ++cc) acc[r][cc] = 0.f;

  // --- v1 = gelu(hE @ Wv1 + bv1), K = 256 ---
  for (int kc = 0; kc < 16; ++kc) {
    const int k0 = kc * 16;
    const float4 av = *(const float4*)&hE[(e0 + ar) * 256 + k0 + aq];
    const float4 b0 = *(const float4*)&Wv1[(size_t)(k0 + bk) * 128 + bc];
    const float4 b1 = *(const float4*)&Wv1[(size_t)(k0 + bk) * 128 + bc + 4];
    __syncthreads();
    As[ar][aq+0] = av.x; As[ar][aq+1] = av.y; As[ar][aq+2] = av.z; As[ar][aq+3] = av.w;
    *(float4*)&Bs[bk][bc] = b0;
    *(float4*)&Bs[bk][bc + 4] = b1;
    __syncthreads();
#pragma unroll
    for (int k = 0; k < 16; ++k) {
      const float a0 = As[tm*4+0][k], a1 = As[tm*4+1][k];
      const float a2 = As[tm*4+2][k], a3 = As[tm*4+3][k];
      const float4 p = *(const float4*)&Bs[k][tn*4];
      const float4 q = *(const float4*)&Bs[k][64 + tn*4];
      INNER_FMA(a0,a1,a2,a3,p,q)
    }
  }
  {
    const int cA = tn*4, cB = 64 + tn*4;
#pragma unroll
    for (int r = 0; r < 4; ++r) {
      const int row = tm*4 + r;
#pragma unroll
      for (int i = 0; i < 4; ++i) {
        X[row][cA+i] = gelu_exact(acc[r][i]   + bv1[cA+i]);
        X[row][cB+i] = gelu_exact(acc[r][4+i] + bv1[cB+i]);
        acc[r][i] = 0.f; acc[r][4+i] = 0.f;
      }
    }
  }
  // --- v2 = gelu(v1 @ Wv2 + bv2), K = 128 ---
  for (int kc = 0; kc < 8; ++kc) {
    const int k0 = kc * 16;
    const float4 b0 = *(const float4*)&Wv2[(size_t)(k0 + bk) * 128 + bc];
    const float4 b1 = *(const float4*)&Wv2[(size_t)(k0 + bk) * 128 + bc + 4];
    __syncthreads();
    *(float4*)&Bs[bk][bc] = b0;
    *(float4*)&Bs[bk][bc + 4] = b1;
    __syncthreads();
#pragma unroll
    for (int k = 0; k < 16; ++k) {
      const int kk = k0 + k;
      const float a0 = X[tm*4+0][kk], a1 = X[tm*4+1][kk];
      const float a2 = X[tm*4+2][kk], a3 = X[tm*4+3][kk];
      const float4 p = *(const float4*)&Bs[k][tn*4];
      const float4 q = *(const float4*)&Bs[k][64 + tn*4];
      INNER_FMA(a0,a1,a2,a3,p,q)
    }
  }
  __syncthreads();
  {
    const int cA = tn*4, cB = 64 + tn*4;
#pragma unroll
    for (int r = 0; r < 4; ++r) {
      const int row = tm*4 + r;
#pragma unroll
      for (int i = 0; i < 4; ++i) {
        X[row][cA+i] = gelu_exact(acc[r][i]   + bv2[cA+i]);
        X[row][cB+i] = gelu_exact(acc[r][4+i] + bv2[cB+i]);
        acc[r][i] = 0.f; acc[r][4+i] = 0.f;
      }
    }
  }
  __syncthreads();
  // --- V = v2 @ Wv3 + bv3, K = 128 ---
  for (int kc = 0; kc < 8; ++kc) {
    const int k0 = kc * 16;
    const float4 b0 = *(const float4*)&Wv3[(size_t)(k0 + bk) * 128 + bc];
    const float4 b1 = *(const float4*)&Wv3[(size_t)(k0 + bk) * 128 + bc + 4];
    __syncthreads();
    *(float4*)&Bs[bk][bc] = b0;
    *(float4*)&Bs[bk][bc + 4] = b1;
    __syncthreads();
#pragma unroll
    for (int k = 0; k < 16; ++k) {
      const int kk = k0 + k;
      const float a0 = X[tm*4+0][kk], a1 = X[tm*4+1][kk];
      const float a2 = X[tm*4+2][kk], a3 = X[tm*4+3][kk];
      const float4 p = *(const float4*)&Bs[k][tn*4];
      const float4 q = *(const float4*)&Bs[k][64 + tn*4];
      INNER_FMA(a0,a1,a2,a3,p,q)
    }
  }
  {
    const int cA = tn*4, cB = 64 + tn*4;
#pragma unroll
    for (int r = 0; r < 4; ++r) {
      const size_t row = e0 + tm*4 + r;
      float4 u = make_float4(acc[r][0]+bv3[cA+0], acc[r][1]+bv3[cA+1],
                             acc[r][2]+bv3[cA+2], acc[r][3]+bv3[cA+3]);
      float4 v = make_float4(acc[r][4]+bv3[cB+0], acc[r][5]+bv3[cB+1],
                             acc[r][6]+bv3[cB+2], acc[r][7]+bv3[cB+3]);
      *(float4*)&Vout[row * 128 + cA] = u;
      *(float4*)&Vout[row * 128 + cB] = v;
    }
  }
}

// ======================= 6-8. CSR build =======================
__global__ __launch_bounds__(256) void count_edges(const int* __restrict__ eidx,
                                                   int* __restrict__ counts) {
  const int e = blockIdx.x * 256 + threadIdx.x;
  atomicAdd(&counts[eidx[e]], 1);
}

__global__ __launch_bounds__(1024) void scan_kernel(const int* __restrict__ counts,
                                                    int* __restrict__ row_start,
                                                    int* __restrict__ cursor) {
  __shared__ int buf[1024];
  __shared__ int carry;
  const int tid = threadIdx.x;
  if (tid == 0) carry = 0;
  __syncthreads();
  for (int base = 0; base < NN; base += 1024) {
    const int i = base + tid;
    const int v = (i < NN) ? counts[i] : 0;
    buf[tid] = v;
    __syncthreads();
    for (int off = 1; off < 1024; off <<= 1) {
      const int t = (tid >= off) ? buf[tid - off] : 0;
      __syncthreads();
      buf[tid] += t;
      __syncthreads();
    }
    const int excl = buf[tid] - v;
    if (i < NN) { row_start[i] = carry + excl; cursor[i] = carry + excl; }
    const int total = buf[1023];
    __syncthreads();
    if (tid == 0) carry += total;
    __syncthreads();
  }
  if (tid == 0) row_start[NN] = carry;   // == NE
}

__global__ __launch_bounds__(256) void scatter_edges(const int* __restrict__ eidx,
                                                     int* __restrict__ cursor,
                                                     int* __restrict__ edge_list) {
  const int e = blockIdx.x * 256 + threadIdx.x;
  const int c = eidx[e];
  const int pos = atomicAdd(&cursor[c], 1);
  edge_list[pos] = e;
}

// ======================= 9. segment softmax + aggregation =======================
// one 64-lane wave per node; 4 waves per block
__global__ __launch_bounds__(256) void agg_kernel(
    const int* __restrict__ row_start, const int* __restrict__ edge_list,
    const float* __restrict__ logits, const float* __restrict__ V,
    float* __restrict__ h_agg)
{
  const int wave = threadIdx.x >> 6, lane = threadIdx.x & 63;
  const int n = blockIdx.x * 4 + wave;
  const int beg = row_start[n], end = row_start[n + 1];
  float m[4] = {-1e30f, -1e30f, -1e30f, -1e30f};
  float s[4] = {0.f, 0.f, 0.f, 0.f};
  for (int idx = beg + lane; idx < end; idx += 64) {
    const int e = edge_list[idx];
    const float4 l4 = *(const float4*)&logits[(size_t)e * 4];
    const float lv[4] = {l4.x, l4.y, l4.z, l4.w};
#pragma unroll
    for (int h = 0; h < 4; ++h) {
      if (lv[h] > m[h]) { s[h] = s[h] * expf(m[h] - lv[h]) + 1.f; m[h] = lv[h]; }
      else s[h] += expf(lv[h] - m[h]);
    }
  }
#pragma unroll
  for (int off = 1; off < 64; off <<= 1) {
#pragma unroll
    for (int h = 0; h < 4; ++h) {
      const float mo = __shfl_xor(m[h], off);
      const float so = __shfl_xor(s[h], off);
      const float mn = fmaxf(m[h], mo);
      s[h] = s[h] * expf(m[h] - mn) + so * expf(mo - mn);
      m[h] = mn;
    }
  }
  const int h = lane >> 4;                 // output dims 2*lane, 2*lane+1 -> head lane/16
  const float mh = m[h];
  const float inv_s = (s[h] > 0.f) ? 1.f / s[h] : 0.f;
  float2 acc = {0.f, 0.f};
  for (int idx = beg; idx < end; ++idx) {
    const int e = edge_list[idx];
    const float att = expf(logits[(size_t)e * 4 + h] - mh) * inv_s;
    const float2 v2 = *(const float2*)&V[(size_t)e * 128 + lane * 2];
    acc.x = fmaf(att, v2.x, acc.x);
    acc.y = fmaf(att, v2.y, acc.y);
  }
  *(float2*)&h_agg[(size_t)n * 128 + lane * 2] = acc;
}

// ======================= 10. out = h_agg @ W_O =======================
__global__ __launch_bounds__(256) void out_gemm(const float* __restrict__ h_agg,
                                                const float* __restrict__ WO,
                                                float* __restrict__ out) {
  __shared__ float A[16 * 128];
  const size_t r0 = (size_t)blockIdx.x * 16;
  for (int i = threadIdx.x; i < 16 * 128 / 4; i += 256)
    ((float4*)A)[i] = ((const float4*)(h_agg + r0 * 128))[i];
  __syncthreads();
  const int c = threadIdx.x & 127, rg = threadIdx.x >> 7;
  float acc[8] = {0,0,0,0,0,0,0,0};
  for (int k = 0; k < 128; ++k) {
    const float w = WO[k * 128 + c];
#pragma unroll
    for (int r = 0; r < 8; ++r) acc[r] = fmaf(A[(rg * 8 + r) * 128 + k], w, acc[r]);
  }
#pragma unroll
  for (int r = 0; r < 8; ++r) out[(r0 + rg * 8 + r) * 128 + c] = acc[r];
}

// ======================= launch =======================
extern "C" void kernel_launch(void* const* d_in, const int* in_sizes, int n_in,
                              void* d_out, int out_size, void* d_ws, size_t ws_size,
                              hipStream_t stream)
{
  const float* hV     = (const float*)d_in[0];
  const float* hEin   = (const float*)d_in[1];
  const int*   eidx   = (const int*)d_in[2];
  const float* hVv    = (const float*)d_in[3];
  const float* frames = (const float*)d_in[4];
  const float* Wvec   = (const float*)d_in[5];
  const float* Wred   = (const float*)d_in[6];
  const float* Wb1    = (const float*)d_in[7];
  const float* bb1    = (const float*)d_in[8];
  const float* Wb2    = (const float*)d_in[9];
  const float* bb2    = (const float*)d_in[10];
  const float* Wb3    = (const float*)d_in[11];
  const float* bb3    = (const float*)d_in[12];
  const float* Wv1    = (const float*)d_in[13];
  const float* bv1    = (const float*)d_in[14];
  const float* Wv2    = (const float*)d_in[15];
  const float* bv2    = (const float*)d_in[16];
  const float* Wv3    = (const float*)d_in[17];
  const float* bv3    = (const float*)d_in[18];
  const float* WO     = (const float*)d_in[19];
  const float* bng    = (const float*)d_in[20];
  const float* bnb    = (const float*)d_in[21];
  float* out = (float*)d_out;

  float* ws      = (float*)d_ws;
  float* vff     = ws;                              // E*64
  float* partial = vff + (size_t)NE * 64;           // 5000*32
  float* bnp     = partial + 160000;                // 64
  float* hEmid   = bnp + 64;                        // E*256
  float* logits  = hEmid + (size_t)NE * 256;        // E*4
  float* Vbuf    = logits + (size_t)NE * 4;         // E*128
  float* hagg    = Vbuf + (size_t)NE * 128;         // N*128
  int* counts    = (int*)(hagg + (size_t)NN * 128); // N
  int* row_start = counts + 10016;                  // N+1
  int* cursor    = row_start + 10016;               // N
  int* edge_list = cursor + 10016;                  // E

  hipMemsetAsync(counts, 0, NN * sizeof(int), stream);
  geom_kernel<<<5000, 256, 0, stream>>>(hVv, eidx, frames, Wvec, vff, partial);
  bn_finalize<<<1, 512, 0, stream>>>(partial, bng, bnb, bnp);
  gemm_hE<<<dim3(5000, 2), 256, 0, stream>>>(vff, hEin, Wred, bnp, hEmid);
  attn_mlp<<<5000, 256, 0, stream>>>(hEmid, hV, eidx, Wb1, bb1, Wb2, bb2, Wb3, bb3, logits);
  v_mlp<<<5000, 256, 0, stream>>>(hEmid, Wv1, bv1, Wv2, bv2, Wv3, bv3, Vbuf);
  count_edges<<<1250, 256, 0, stream>>>(eidx, counts);
  scan_kernel<<<1, 1024, 0, stream>>>(counts, row_start, cursor);
  scatter_edges<<<1250, 256, 0, stream>>>(eidx, cursor, edge_list);
  agg_kernel<<<2500, 256, 0, stream>>>(row_start, edge_list, logits, Vbuf, hagg);
  out_gemm<<<625, 256, 0, stream>>>(hagg, WO, out);
}